// Round 15
// baseline (55.676 us; speedup 1.0000x reference)
//
#include <hip/hip_runtime.h>
#include <hip/hip_bf16.h>

#define B_ 32
#define D_ 512
#define N_ 1024
#define M_ 1024
#define BT 256
#define BK 64
#define NSTEP (D_ / BK)   // 8

typedef __attribute__((ext_vector_type(8))) short bf16x8;
typedef __attribute__((ext_vector_type(4))) short s16x4;
typedef __attribute__((ext_vector_type(4))) float f32x4;
typedef __attribute__((ext_vector_type(4))) int   i32x4;
typedef unsigned short ushort_t;

__device__ __forceinline__ unsigned map_f(float f) {
    unsigned b = __float_as_uint(f);
    return (b & 0x80000000u) ? ~b : (b | 0x80000000u);
}

// ============================================================================
// Fused fp32->bf16 GEMM-max, 256x256 tile, 8 waves, double-buffered LDS.
// R14 base + 4-phase interleaved K-step (16 MFMA per phase; next phase's
// tr_reads and the staging ds_writes issued BEFORE the counted lgkmcnt wait,
// so the LDS unit streams under the MFMA pipe instead of serializing).
// Counted-wait ledger per step (issue order => in-order completion):
//   top   : a0 (A kk0 h0, 8) + b0 (B kk0, 8)
//   phase0: issue a1 (A kk0 h1, 8); lgkmcnt(8)  -> a0,b0 done; MFMA acc[0-3]
//   phase1: lgkmcnt(0) -> a1 done; issue a0 (A kk1 h0, 8);     MFMA acc[4-7]
//   phase2: issue b1 (B kk1, 8), a1 (A kk1 h1, 8), flushA'(4w), loadB';
//           lgkmcnt(12) -> a0,b1 done (a1+flushA in flight);   MFMA acc[0-3]
//   phase3: lgkmcnt(4)  -> a1 done (flushA <=4 pending);       MFMA acc[4-7]
//           flushB'(4w), loadA''; lgkmcnt(0); s_barrier
// ============================================================================
struct __align__(16) GSmem {
    ushort_t As[2][BT * BK];   // 32KB each: As[0]@0, As[1]@32768
    ushort_t Bs[2][BT * BK];   // Bs[0]@65536, Bs[1]@98304
    float red[8];
};

__device__ __forceinline__ void load_tile(const float* __restrict__ p, int k0,
                                          int krb, int gr, float4* fl) {
    #pragma unroll
    for (int it = 0; it < 4; ++it) {
        const float* q = p + (size_t)(k0 + krb + it) * N_ + gr * 8;
        fl[2 * it]     = *reinterpret_cast<const float4*>(q);
        fl[2 * it + 1] = *reinterpret_cast<const float4*>(q + 4);
    }
}

__device__ __forceinline__ void flush_tile(char* lds, int krb, int gr, const float4* fl) {
    #pragma unroll
    for (int it = 0; it < 4; ++it) {
        const int k = krb + it;
        const float4& f0 = fl[2 * it];
        const float4& f1 = fl[2 * it + 1];
        __hip_bfloat162 h0 = __float22bfloat162_rn(make_float2(f0.x, f0.y));
        __hip_bfloat162 h1 = __float22bfloat162_rn(make_float2(f0.z, f0.w));
        __hip_bfloat162 h2 = __float22bfloat162_rn(make_float2(f1.x, f1.y));
        __hip_bfloat162 h3 = __float22bfloat162_rn(make_float2(f1.z, f1.w));
        i32x4 v = { *reinterpret_cast<const int*>(&h0), *reinterpret_cast<const int*>(&h1),
                    *reinterpret_cast<const int*>(&h2), *reinterpret_cast<const int*>(&h3) };
        *reinterpret_cast<i32x4*>(lds + k * 512 + 16 * (gr ^ (2 * (k & 3)))) = v;
    }
}

#define ISSUE_A(lo, hi, base_m, kkoff)                                          \
    _Pragma("unroll")                                                           \
    for (int mm = 0; mm < 4; ++mm) {                                            \
        asm volatile("ds_read_b64_tr_b16 %0, %1 offset:%2"                      \
                     : "=v"(lo[mm]) : "v"(tbA[(base_m) + mm] + off), "n"(kkoff));\
        asm volatile("ds_read_b64_tr_b16 %0, %1 offset:%2"                      \
                     : "=v"(hi[mm]) : "v"(tbA[(base_m) + mm] + off), "n"((kkoff) + 2048)); \
    }

#define ISSUE_B(lo, hi, kkoff)                                                  \
    _Pragma("unroll")                                                           \
    for (int nn = 0; nn < 4; ++nn) {                                            \
        asm volatile("ds_read_b64_tr_b16 %0, %1 offset:%2"                      \
                     : "=v"(lo[nn]) : "v"(tbB[nn] + off), "n"(kkoff));          \
        asm volatile("ds_read_b64_tr_b16 %0, %1 offset:%2"                      \
                     : "=v"(hi[nn]) : "v"(tbB[nn] + off), "n"((kkoff) + 2048)); \
    }

#define MFMA16(alo_, ahi_, bf_, mb)                                             \
    {                                                                           \
        bf16x8 af_[4];                                                          \
        _Pragma("unroll")                                                       \
        for (int mm = 0; mm < 4; ++mm)                                          \
            af_[mm] = __builtin_shufflevector(alo_[mm], ahi_[mm], 0,1,2,3,4,5,6,7); \
        __builtin_amdgcn_s_setprio(1);                                          \
        _Pragma("unroll")                                                       \
        for (int mm = 0; mm < 4; ++mm)                                          \
            _Pragma("unroll")                                                   \
            for (int nn = 0; nn < 4; ++nn)                                      \
                acc[(mb) + mm][nn] = __builtin_amdgcn_mfma_f32_16x16x32_bf16(   \
                    af_[mm], bf_[nn], acc[(mb) + mm][nn], 0, 0, 0);             \
        __builtin_amdgcn_s_setprio(0);                                          \
    }

__global__ __launch_bounds__(512, 2)
void fused_gemm_max_kernel(const float* __restrict__ e1, const float* __restrict__ e2,
                           float* __restrict__ out) {
    __shared__ GSmem sm;
    const int wg  = blockIdx.x;
    const int swz = (wg & 7) * 64 + (wg >> 3);   // XCD swizzle (512 % 8 == 0)
    const int b    = swz >> 4;
    const int tile = swz & 15;
    const int tn = (tile >> 2) * BT;
    const int tc = (tile & 3) * BT;

    const int t    = threadIdx.x;
    const int lane = t & 63;
    const int wave = t >> 6;
    const int wrow = (wave >> 2) * 128;
    const int wcol = (wave & 3) * 64;

    const int krb = (t >> 5) * 4;
    const int gr  = t & 31;

    const int c = lane & 15, g = lane >> 4;
    const int r = c >> 2, d = (c >> 1) & 1, h = c & 1;

    unsigned tbA[8], tbB[4];
    #pragma unroll
    for (int m = 0; m < 8; ++m)
        tbA[m] = (unsigned)((8 * g + r) * 512
               + 16 * ((((wrow >> 3) + 2 * m + d) ^ (2 * r))) + 8 * h);
    #pragma unroll
    for (int n = 0; n < 4; ++n)
        tbB[n] = (unsigned)(65536 + (8 * g + r) * 512
               + 16 * ((((wcol >> 3) + 2 * n + d) ^ (2 * r))) + 8 * h);
    const unsigned ldsbase = (unsigned)(uintptr_t)&sm.As[0][0];

    const float* Ap = e1 + (size_t)b * D_ * N_ + tn;
    const float* Bp = e2 + (size_t)b * D_ * M_ + tc;

    f32x4 acc[8][4] = {};
    float4 fl[8];

    // Prologue: A0 -> LDS0, B0 -> LDS0, issue A1 loads into fl.
    load_tile(Ap, 0, krb, gr, fl);
    flush_tile((char*)sm.As[0], krb, gr, fl);
    load_tile(Bp, 0, krb, gr, fl);
    flush_tile((char*)sm.Bs[0], krb, gr, fl);
    load_tile(Ap, BK, krb, gr, fl);
    asm volatile("s_waitcnt lgkmcnt(0)" ::: "memory");
    __builtin_amdgcn_s_barrier();

    int cur = 0;
    #pragma unroll 1
    for (int ks = 0; ks < NSTEP; ++ks) {
        const unsigned off = ldsbase + (unsigned)cur * 32768u;
        const bool has_next = (ks < NSTEP - 1);

        s16x4 a0lo[4], a0hi[4], a1lo[4], a1hi[4];
        s16x4 b0lo[4], b0hi[4], b1lo[4], b1hi[4];

        // top: P0 operands
        ISSUE_A(a0lo, a0hi, 0, 0)
        ISSUE_B(b0lo, b0hi, 0)

        // ---- phase 0: kk0, m0-3 ----
        ISSUE_A(a1lo, a1hi, 4, 0)                      // A(kk0,h1) in flight
        asm volatile("s_waitcnt lgkmcnt(8)" ::: "memory");
        __builtin_amdgcn_sched_barrier(0);
        bf16x8 bf0[4];
        #pragma unroll
        for (int nn = 0; nn < 4; ++nn)
            bf0[nn] = __builtin_shufflevector(b0lo[nn], b0hi[nn], 0,1,2,3,4,5,6,7);
        MFMA16(a0lo, a0hi, bf0, 0)

        // ---- phase 1: kk0, m4-7 ----
        asm volatile("s_waitcnt lgkmcnt(0)" ::: "memory");   // a1 done
        __builtin_amdgcn_sched_barrier(0);
        ISSUE_A(a0lo, a0hi, 0, 16384)                  // A(kk1,h0) in flight
        MFMA16(a1lo, a1hi, bf0, 4)

        // ---- phase 2: kk1, m0-3 ----
        ISSUE_B(b1lo, b1hi, 16384)                     // B(kk1)
        ISSUE_A(a1lo, a1hi, 4, 16384)                  // A(kk1,h1)
        if (has_next) {
            flush_tile((char*)sm.As[cur ^ 1], krb, gr, fl);   // A(ks+1) -> LDS'
            load_tile(Bp, (ks + 1) * BK, krb, gr, fl);        // issue B(ks+1) globals
        }
        asm volatile("s_waitcnt lgkmcnt(12)" ::: "memory");   // a0,b1 done
        __builtin_amdgcn_sched_barrier(0);
        bf16x8 bf1[4];
        #pragma unroll
        for (int nn = 0; nn < 4; ++nn)
            bf1[nn] = __builtin_shufflevector(b1lo[nn], b1hi[nn], 0,1,2,3,4,5,6,7);
        MFMA16(a0lo, a0hi, bf1, 0)

        // ---- phase 3: kk1, m4-7 ----
        if (has_next)
            asm volatile("s_waitcnt lgkmcnt(4)" ::: "memory");  // a1 done, flushA pending
        else
            asm volatile("s_waitcnt lgkmcnt(0)" ::: "memory");
        __builtin_amdgcn_sched_barrier(0);
        MFMA16(a1lo, a1hi, bf1, 4)
        if (has_next) {
            flush_tile((char*)sm.Bs[cur ^ 1], krb, gr, fl);   // B(ks+1) -> LDS'
            if (ks < NSTEP - 2)
                load_tile(Ap, (ks + 2) * BK, krb, gr, fl);    // issue A(ks+2) globals
        }
        asm volatile("s_waitcnt lgkmcnt(0)" ::: "memory");
        __builtin_amdgcn_s_barrier();
        cur ^= 1;
    }

    // Max over this thread's 128 accumulator values.
    float tmax = acc[0][0][0];
    #pragma unroll
    for (int m = 0; m < 8; ++m)
        #pragma unroll
        for (int n = 0; n < 4; ++n)
            #pragma unroll
            for (int i = 0; i < 4; ++i)
                tmax = fmaxf(tmax, acc[m][n][i]);
    #pragma unroll
    for (int off2 = 32; off2; off2 >>= 1)
        tmax = fmaxf(tmax, __shfl_xor(tmax, off2));
    if (lane == 0) sm.red[wave] = tmax;
    __syncthreads();
    if (t == 0) {
        float m8 = sm.red[0];
        #pragma unroll
        for (int w = 1; w < 8; ++w) m8 = fmaxf(m8, sm.red[w]);
        atomicMax(reinterpret_cast<unsigned*>(out) + b, map_f(m8));
    }
}

__global__ void finalize_kernel(float* out) {
    const int i = threadIdx.x;
    unsigned u = reinterpret_cast<unsigned*>(out)[i];
    out[i] = __uint_as_float((u & 0x80000000u) ? (u ^ 0x80000000u) : ~u);
}

extern "C" void kernel_launch(void* const* d_in, const int* in_sizes, int n_in,
                              void* d_out, int out_size, void* d_ws, size_t ws_size,
                              hipStream_t stream) {
    const float* e1 = (const float*)d_in[0];
    const float* e2 = (const float*)d_in[1];
    float* out = (float*)d_out;

    (void)hipMemsetAsync(d_out, 0, B_ * sizeof(float), stream);  // 0 == -inf under map_f

    fused_gemm_max_kernel<<<dim3(512), 512, 0, stream>>>(e1, e2, out);
    finalize_kernel<<<1, B_, 0, stream>>>(out);
}

// Round 16
// 54.379 us; speedup vs baseline: 1.0238x; 1.0238x over previous
//
#include <hip/hip_runtime.h>
#include <hip/hip_bf16.h>

#define B_ 32
#define D_ 512
#define N_ 1024
#define M_ 1024
#define BT 256
#define BK 64
#define NSTEP (D_ / BK)   // 8

typedef __attribute__((ext_vector_type(8)))  short bf16x8;
typedef __attribute__((ext_vector_type(4)))  short s16x4;
typedef __attribute__((ext_vector_type(4)))  float f32x4;
typedef __attribute__((ext_vector_type(16))) float f32x16;
typedef __attribute__((ext_vector_type(4)))  int   i32x4;
typedef unsigned short ushort_t;

__device__ __forceinline__ unsigned map_f(float f) {
    unsigned b = __float_as_uint(f);
    return (b & 0x80000000u) ? ~b : (b | 0x80000000u);
}

// ============================================================================
// Fused fp32->bf16 GEMM-max, 256x256 tile, 8 waves, double-buffered LDS.
// R14 base (verified 52.7us) with ONE change: 32x32x16 MFMA (m119: 2495 vs
// 2075 TF; half the MFMA instructions).  Per wave: 4x2 frags of 32x32,
// 4 K-slices (K=16 each) per BK=64 step.
// LDS tile [k=64][j=256] bf16, rows 512B = 32 granules; granule gr of row k
// at byte k*512 + 16*(gr ^ (2*(k&3))) (R8-verified layout, scaled).
// tr_read frag mapping (derived from R5-verified 16x16 formula):
//   lane l = c + 16*g (c=l&15, g=l>>4); r=c>>2, d=(c>>1)&1, h=c&1
//   32x32: j = JB + 32*mi + 16*(g&1) + (c-bits), k = 8*(g>>1) + elem
//   addr  = (8*(g>>1)+r)*512 + 16*(((JB>>3)+4*mi+2*(g&1)+d) ^ (2r)) + 8h
//   hi: +2048 (k+4);  K-slice ksl: +8192*ksl (k+16 per slice)
// ============================================================================
struct __align__(16) GSmem {
    ushort_t As[2][BT * BK];   // 32KB each: As[0]@0, As[1]@32768
    ushort_t Bs[2][BT * BK];   // Bs[0]@65536, Bs[1]@98304
    float red[8];
};

__device__ __forceinline__ void load_tile(const float* __restrict__ p, int k0,
                                          int krb, int gr, float4* fl) {
    #pragma unroll
    for (int it = 0; it < 4; ++it) {
        const float* q = p + (size_t)(k0 + krb + it) * N_ + gr * 8;
        fl[2 * it]     = *reinterpret_cast<const float4*>(q);
        fl[2 * it + 1] = *reinterpret_cast<const float4*>(q + 4);
    }
}

__device__ __forceinline__ void flush_tile(char* lds, int krb, int gr, const float4* fl) {
    #pragma unroll
    for (int it = 0; it < 4; ++it) {
        const int k = krb + it;
        const float4& f0 = fl[2 * it];
        const float4& f1 = fl[2 * it + 1];
        __hip_bfloat162 h0 = __float22bfloat162_rn(make_float2(f0.x, f0.y));
        __hip_bfloat162 h1 = __float22bfloat162_rn(make_float2(f0.z, f0.w));
        __hip_bfloat162 h2 = __float22bfloat162_rn(make_float2(f1.x, f1.y));
        __hip_bfloat162 h3 = __float22bfloat162_rn(make_float2(f1.z, f1.w));
        i32x4 v = { *reinterpret_cast<const int*>(&h0), *reinterpret_cast<const int*>(&h1),
                    *reinterpret_cast<const int*>(&h2), *reinterpret_cast<const int*>(&h3) };
        *reinterpret_cast<i32x4*>(lds + k * 512 + 16 * (gr ^ (2 * (k & 3)))) = v;
    }
}

__global__ __launch_bounds__(512, 2)
void fused_gemm_max_kernel(const float* __restrict__ e1, const float* __restrict__ e2,
                           float* __restrict__ out) {
    __shared__ GSmem sm;
    const int wg  = blockIdx.x;
    const int swz = (wg & 7) * 64 + (wg >> 3);   // XCD swizzle (512 % 8 == 0)
    const int b    = swz >> 4;
    const int tile = swz & 15;
    const int tn = (tile >> 2) * BT;
    const int tc = (tile & 3) * BT;

    const int t    = threadIdx.x;
    const int lane = t & 63;
    const int wave = t >> 6;
    const int wrow = (wave >> 2) * 128;          // A j-offset
    const int wcol = (wave & 3) * 64;            // B j-offset

    const int krb = (t >> 5) * 4;
    const int gr  = t & 31;

    // tr_read per-lane geometry (32x32 variant of the R5-verified mapping)
    const int c = lane & 15, g = lane >> 4;
    const int r = c >> 2, d = (c >> 1) & 1, h = c & 1;
    const int kg = g >> 1;        // k-group: 0,1 -> k-base 8*kg
    const int jh = g & 1;         // j-half: +16 cols, granule +2

    unsigned tbA[4], tbB[2];
    #pragma unroll
    for (int mi = 0; mi < 4; ++mi)
        tbA[mi] = (unsigned)((8 * kg + r) * 512
                + 16 * ((((wrow >> 3) + 4 * mi + 2 * jh + d) ^ (2 * r))) + 8 * h);
    #pragma unroll
    for (int ni = 0; ni < 2; ++ni)
        tbB[ni] = (unsigned)(65536 + (8 * kg + r) * 512
                + 16 * ((((wcol >> 3) + 4 * ni + 2 * jh + d) ^ (2 * r))) + 8 * h);
    const unsigned ldsbase = (unsigned)(uintptr_t)&sm.As[0][0];

    const float* Ap = e1 + (size_t)b * D_ * N_ + tn;
    const float* Bp = e2 + (size_t)b * D_ * M_ + tc;

    f32x16 acc[4][2] = {};
    float4 fl[8];

    // Prologue: A0 -> LDS0, B0 -> LDS0, issue A1 loads into fl.
    load_tile(Ap, 0, krb, gr, fl);
    flush_tile((char*)sm.As[0], krb, gr, fl);
    load_tile(Bp, 0, krb, gr, fl);
    flush_tile((char*)sm.Bs[0], krb, gr, fl);
    load_tile(Ap, BK, krb, gr, fl);
    asm volatile("s_waitcnt lgkmcnt(0)" ::: "memory");
    __builtin_amdgcn_s_barrier();

    int cur = 0;
    #pragma unroll 1
    for (int ks = 0; ks < NSTEP; ++ks) {
        const unsigned off = ldsbase + (unsigned)cur * 32768u;
        const bool has_next = (ks < NSTEP - 1);

        #pragma unroll
        for (int ksl = 0; ksl < 4; ++ksl) {
            s16x4 alo[4], ahi[4], blo[2], bhi[2];
            #pragma unroll
            for (int mi = 0; mi < 4; ++mi) {
                asm volatile("ds_read_b64_tr_b16 %0, %1 offset:%2"
                             : "=v"(alo[mi]) : "v"(tbA[mi] + off), "n"(ksl * 8192));
                asm volatile("ds_read_b64_tr_b16 %0, %1 offset:%2"
                             : "=v"(ahi[mi]) : "v"(tbA[mi] + off), "n"(ksl * 8192 + 2048));
            }
            #pragma unroll
            for (int ni = 0; ni < 2; ++ni) {
                asm volatile("ds_read_b64_tr_b16 %0, %1 offset:%2"
                             : "=v"(blo[ni]) : "v"(tbB[ni] + off), "n"(ksl * 8192));
                asm volatile("ds_read_b64_tr_b16 %0, %1 offset:%2"
                             : "=v"(bhi[ni]) : "v"(tbB[ni] + off), "n"(ksl * 8192 + 2048));
            }
            asm volatile("s_waitcnt lgkmcnt(0)" ::: "memory");
            __builtin_amdgcn_sched_barrier(0);
            bf16x8 af[4], bf[2];
            #pragma unroll
            for (int mi = 0; mi < 4; ++mi)
                af[mi] = __builtin_shufflevector(alo[mi], ahi[mi], 0, 1, 2, 3, 4, 5, 6, 7);
            #pragma unroll
            for (int ni = 0; ni < 2; ++ni)
                bf[ni] = __builtin_shufflevector(blo[ni], bhi[ni], 0, 1, 2, 3, 4, 5, 6, 7);
            __builtin_amdgcn_s_setprio(1);
            #pragma unroll
            for (int mi = 0; mi < 4; ++mi)
                #pragma unroll
                for (int ni = 0; ni < 2; ++ni)
                    acc[mi][ni] = __builtin_amdgcn_mfma_f32_32x32x16_bf16(
                        af[mi], bf[ni], acc[mi][ni], 0, 0, 0);
            __builtin_amdgcn_s_setprio(0);

            if (ksl == 1 && has_next) {
                flush_tile((char*)sm.As[cur ^ 1], krb, gr, fl);   // A(ks+1) -> LDS'
                load_tile(Bp, (ks + 1) * BK, krb, gr, fl);        // issue B(ks+1) globals
            }
        }
        if (has_next) {
            flush_tile((char*)sm.Bs[cur ^ 1], krb, gr, fl);       // B(ks+1) -> LDS'
            if (ks < NSTEP - 2)
                load_tile(Ap, (ks + 2) * BK, krb, gr, fl);        // issue A(ks+2) globals
        }
        asm volatile("s_waitcnt lgkmcnt(0)" ::: "memory");        // ds_writes drained
        __builtin_amdgcn_s_barrier();
        cur ^= 1;
    }

    // Max over this thread's 128 accumulator values.
    float tmax = acc[0][0][0];
    #pragma unroll
    for (int mi = 0; mi < 4; ++mi)
        #pragma unroll
        for (int ni = 0; ni < 2; ++ni)
            #pragma unroll
            for (int i = 0; i < 16; ++i)
                tmax = fmaxf(tmax, acc[mi][ni][i]);
    #pragma unroll
    for (int off2 = 32; off2; off2 >>= 1)
        tmax = fmaxf(tmax, __shfl_xor(tmax, off2));
    if (lane == 0) sm.red[wave] = tmax;
    __syncthreads();
    if (t == 0) {
        float m8 = sm.red[0];
        #pragma unroll
        for (int w = 1; w < 8; ++w) m8 = fmaxf(m8, sm.red[w]);
        atomicMax(reinterpret_cast<unsigned*>(out) + b, map_f(m8));
    }
}

__global__ void finalize_kernel(float* out) {
    const int i = threadIdx.x;
    unsigned u = reinterpret_cast<unsigned*>(out)[i];
    out[i] = __uint_as_float((u & 0x80000000u) ? (u ^ 0x80000000u) : ~u);
}

extern "C" void kernel_launch(void* const* d_in, const int* in_sizes, int n_in,
                              void* d_out, int out_size, void* d_ws, size_t ws_size,
                              hipStream_t stream) {
    const float* e1 = (const float*)d_in[0];
    const float* e2 = (const float*)d_in[1];
    float* out = (float*)d_out;

    (void)hipMemsetAsync(d_out, 0, B_ * sizeof(float), stream);  // 0 == -inf under map_f

    fused_gemm_max_kernel<<<dim3(512), 512, 0, stream>>>(e1, e2, out);
    finalize_kernel<<<1, B_, 0, stream>>>(out);
}

// Round 17
// 52.700 us; speedup vs baseline: 1.0565x; 1.0319x over previous
//
#include <hip/hip_runtime.h>
#include <hip/hip_bf16.h>

#define B_ 32
#define D_ 512
#define N_ 1024
#define M_ 1024
#define BT 256          // tile edge (both n and m)
#define BK 64
#define NSTEP (D_ / BK)   // 8

typedef __attribute__((ext_vector_type(8))) short bf16x8;
typedef __attribute__((ext_vector_type(4))) short s16x4;
typedef __attribute__((ext_vector_type(4))) float f32x4;
typedef __attribute__((ext_vector_type(4))) int   i32x4;
typedef unsigned short ushort_t;

__device__ __forceinline__ unsigned map_f(float f) {
    unsigned b = __float_as_uint(f);
    return (b & 0x80000000u) ? ~b : (b | 0x80000000u);
}

// ============================================================================
// Fused fp32->bf16 GEMM-max, 256x256 tile, 512 threads (8 waves, 2x4),
// per-wave 128x64 output. Double-buffered LDS (128KB), 1 block/CU.
// == R14 verbatim: the empirical best (52.7 us). ==
// Structure ledger: single-buffer/occupancy (R9,R11), counted-wait pipelines
// (R13,R15), and 32x32 MFMA (R16) all regressed vs this compiler-scheduled
// double-buffered form. Register footprint (~252/wave: 128 acc AGPR + 124
// arch) pins occupancy at 8 waves/CU, so deeper overlap is not expressible
// in this structure.
// LDS tile [k=64][j=256] bf16, rows 512B = 32 granules of 16B; granule gr of
// row k at byte k*512 + 16*(gr ^ (2*(k&3)))  (R8-verified layout, scaled).
// Staging: ONE 32-reg buffer time-shared A/B (flush-A after kk0, flush-B
// after kk1).  tr_read fragment path: row stride 512, hi +2048, kk +16384.
// ============================================================================
struct __align__(16) GSmem {
    ushort_t As[2][BT * BK];   // 32KB each: As[0]@0, As[1]@32768
    ushort_t Bs[2][BT * BK];   // Bs[0]@65536, Bs[1]@98304
    float red[8];
};

// Load this thread's granule-column of a [64][256] fp32 tile: 4 rows x 8 cols.
// krb = (t>>5)*4, gr = t&31.  Per row: 32 lanes cover 1KB contiguously.
__device__ __forceinline__ void load_tile(const float* __restrict__ p, int k0,
                                          int krb, int gr, float4* fl) {
    #pragma unroll
    for (int it = 0; it < 4; ++it) {
        const float* q = p + (size_t)(k0 + krb + it) * N_ + gr * 8;
        fl[2 * it]     = *reinterpret_cast<const float4*>(q);
        fl[2 * it + 1] = *reinterpret_cast<const float4*>(q + 4);
    }
}

// Convert + write this thread's 4 granules into one LDS tile (swizzled, b128).
__device__ __forceinline__ void flush_tile(char* lds, int krb, int gr, const float4* fl) {
    #pragma unroll
    for (int it = 0; it < 4; ++it) {
        const int k = krb + it;
        const float4& f0 = fl[2 * it];
        const float4& f1 = fl[2 * it + 1];
        __hip_bfloat162 h0 = __float22bfloat162_rn(make_float2(f0.x, f0.y));
        __hip_bfloat162 h1 = __float22bfloat162_rn(make_float2(f0.z, f0.w));
        __hip_bfloat162 h2 = __float22bfloat162_rn(make_float2(f1.x, f1.y));
        __hip_bfloat162 h3 = __float22bfloat162_rn(make_float2(f1.z, f1.w));
        i32x4 v = { *reinterpret_cast<const int*>(&h0), *reinterpret_cast<const int*>(&h1),
                    *reinterpret_cast<const int*>(&h2), *reinterpret_cast<const int*>(&h3) };
        *reinterpret_cast<i32x4*>(lds + k * 512 + 16 * (gr ^ (2 * (k & 3)))) = v;
    }
}

__global__ __launch_bounds__(512, 2)
void fused_gemm_max_kernel(const float* __restrict__ e1, const float* __restrict__ e2,
                           float* __restrict__ out) {
    __shared__ GSmem sm;
    const int wg  = blockIdx.x;
    const int swz = (wg & 7) * 64 + (wg >> 3);   // XCD swizzle (512 % 8 == 0)
    const int b    = swz >> 4;                   // 16 tiles per batch (4x4)
    const int tile = swz & 15;
    const int tn = (tile >> 2) * BT;             // e1 column-panel
    const int tc = (tile & 3) * BT;              // e2 column-panel

    const int t    = threadIdx.x;
    const int lane = t & 63;
    const int wave = t >> 6;                     // 0..7
    const int wrow = (wave >> 2) * 128;          // A j-offset (2 groups)
    const int wcol = (wave & 3) * 64;            // B j-offset (4 groups)

    // staging geometry: 512 threads cover [64][256]: 16 row-groups x 32 granules
    const int krb = (t >> 5) * 4;
    const int gr  = t & 31;

    // tr_read per-lane geometry (R5-verified pattern, stride scaled to 512B)
    const int c = lane & 15, g = lane >> 4;
    const int r = c >> 2, d = (c >> 1) & 1, h = c & 1;

    unsigned tbA[8], tbB[4];
    #pragma unroll
    for (int m = 0; m < 8; ++m)
        tbA[m] = (unsigned)((8 * g + r) * 512
               + 16 * ((((wrow >> 3) + 2 * m + d) ^ (2 * r))) + 8 * h);
    #pragma unroll
    for (int n = 0; n < 4; ++n)
        tbB[n] = (unsigned)(65536 + (8 * g + r) * 512
               + 16 * ((((wcol >> 3) + 2 * n + d) ^ (2 * r))) + 8 * h);
    const unsigned ldsbase = (unsigned)(uintptr_t)&sm.As[0][0];

    const float* Ap = e1 + (size_t)b * D_ * N_ + tn;
    const float* Bp = e2 + (size_t)b * D_ * M_ + tc;

    f32x4 acc[8][4] = {};
    float4 fl[8];                                // ONE staging buffer, time-shared

    // Prologue (serial, once): A0 -> LDS0, B0 -> LDS0, then issue A1 loads.
    load_tile(Ap, 0, krb, gr, fl);
    flush_tile((char*)sm.As[0], krb, gr, fl);
    load_tile(Bp, 0, krb, gr, fl);
    flush_tile((char*)sm.Bs[0], krb, gr, fl);
    load_tile(Ap, BK, krb, gr, fl);
    asm volatile("s_waitcnt lgkmcnt(0)" ::: "memory");
    __builtin_amdgcn_s_barrier();

    int cur = 0;
    #pragma unroll 1
    for (int ks = 0; ks < NSTEP; ++ks) {
        const unsigned off = ldsbase + (unsigned)cur * 32768u;
        const bool has_next = (ks < NSTEP - 1);

        #pragma unroll
        for (int kk = 0; kk < 2; ++kk) {
            s16x4 alo[8], ahi[8], blo[4], bhi[4];
            #pragma unroll
            for (int m = 0; m < 8; ++m) {
                asm volatile("ds_read_b64_tr_b16 %0, %1 offset:%2"
                             : "=v"(alo[m]) : "v"(tbA[m] + off), "n"(kk * 16384));
                asm volatile("ds_read_b64_tr_b16 %0, %1 offset:%2"
                             : "=v"(ahi[m]) : "v"(tbA[m] + off), "n"(kk * 16384 + 2048));
            }
            #pragma unroll
            for (int n = 0; n < 4; ++n) {
                asm volatile("ds_read_b64_tr_b16 %0, %1 offset:%2"
                             : "=v"(blo[n]) : "v"(tbB[n] + off), "n"(kk * 16384));
                asm volatile("ds_read_b64_tr_b16 %0, %1 offset:%2"
                             : "=v"(bhi[n]) : "v"(tbB[n] + off), "n"(kk * 16384 + 2048));
            }
            asm volatile("s_waitcnt lgkmcnt(0)" ::: "memory");
            __builtin_amdgcn_sched_barrier(0);
            bf16x8 af[8], bf[4];
            #pragma unroll
            for (int m = 0; m < 8; ++m)
                af[m] = __builtin_shufflevector(alo[m], ahi[m], 0, 1, 2, 3, 4, 5, 6, 7);
            #pragma unroll
            for (int n = 0; n < 4; ++n)
                bf[n] = __builtin_shufflevector(blo[n], bhi[n], 0, 1, 2, 3, 4, 5, 6, 7);
            __builtin_amdgcn_s_setprio(1);
            #pragma unroll
            for (int m = 0; m < 8; ++m)
                #pragma unroll
                for (int n = 0; n < 4; ++n)
                    acc[m][n] = __builtin_amdgcn_mfma_f32_16x16x32_bf16(
                        af[m], bf[n], acc[m][n], 0, 0, 0);
            __builtin_amdgcn_s_setprio(0);

            // Time-shared staging between the two MFMA clusters:
            if (kk == 0 && has_next) {
                flush_tile((char*)sm.As[cur ^ 1], krb, gr, fl);  // A(ks+1) -> LDS
                load_tile(Bp, (ks + 1) * BK, krb, gr, fl);       // issue B(ks+1) loads
            }
        }
        if (has_next) {
            flush_tile((char*)sm.Bs[cur ^ 1], krb, gr, fl);      // B(ks+1) -> LDS
            if (ks < NSTEP - 2)
                load_tile(Ap, (ks + 2) * BK, krb, gr, fl);       // issue A(ks+2) loads
        }
        asm volatile("s_waitcnt lgkmcnt(0)" ::: "memory");       // ds_writes drained
        __builtin_amdgcn_s_barrier();
        cur ^= 1;
    }

    // Max over this thread's 128 accumulator values.
    float tmax = acc[0][0][0];
    #pragma unroll
    for (int m = 0; m < 8; ++m)
        #pragma unroll
        for (int n = 0; n < 4; ++n)
            #pragma unroll
            for (int i = 0; i < 4; ++i)
                tmax = fmaxf(tmax, acc[m][n][i]);
    #pragma unroll
    for (int off2 = 32; off2; off2 >>= 1)
        tmax = fmaxf(tmax, __shfl_xor(tmax, off2));
    if (lane == 0) sm.red[wave] = tmax;
    __syncthreads();
    if (t == 0) {
        float m8 = sm.red[0];
        #pragma unroll
        for (int w = 1; w < 8; ++w) m8 = fmaxf(m8, sm.red[w]);
        atomicMax(reinterpret_cast<unsigned*>(out) + b, map_f(m8));
    }
}

__global__ void finalize_kernel(float* out) {
    const int i = threadIdx.x;
    unsigned u = reinterpret_cast<unsigned*>(out)[i];
    out[i] = __uint_as_float((u & 0x80000000u) ? (u ^ 0x80000000u) : ~u);
}

extern "C" void kernel_launch(void* const* d_in, const int* in_sizes, int n_in,
                              void* d_out, int out_size, void* d_ws, size_t ws_size,
                              hipStream_t stream) {
    const float* e1 = (const float*)d_in[0];
    const float* e2 = (const float*)d_in[1];
    float* out = (float*)d_out;

    (void)hipMemsetAsync(d_out, 0, B_ * sizeof(float), stream);  // 0 == -inf under map_f

    fused_gemm_max_kernel<<<dim3(512), 512, 0, stream>>>(e1, e2, out);
    finalize_kernel<<<1, B_, 0, stream>>>(out);
}

// Round 18
// 52.653 us; speedup vs baseline: 1.0574x; 1.0009x over previous
//
#include <hip/hip_runtime.h>
#include <hip/hip_bf16.h>

#define B_ 32
#define D_ 512
#define N_ 1024
#define M_ 1024
#define BT 256
#define BK 64
#define NSTEP (D_ / BK)   // 8

typedef __attribute__((ext_vector_type(8))) short bf16x8;
typedef __attribute__((ext_vector_type(4))) short s16x4;
typedef __attribute__((ext_vector_type(4))) float f32x4;
typedef __attribute__((ext_vector_type(4))) int   i32x4;
typedef unsigned short ushort_t;

__device__ __forceinline__ unsigned map_f(float f) {
    unsigned b = __float_as_uint(f);
    return (b & 0x80000000u) ? ~b : (b | 0x80000000u);
}

// ============================================================================
// Fused fp32->bf16 GEMM-max, 256x256 tile, 8 waves, double-buffered LDS.
// R14 structure (verified 52.7us) with ONE change: the compute phase is
// COMPILER-SCHEDULED. tr_reads go through the gfx950 builtin (if present)
// instead of inline asm + hard lgkmcnt(0) + sched_barrier(0) + setprio.
// The compiler then interleaves reads/cvt/MFMA with its own counted waits
// (as it demonstrably does for plain ds_read -> MFMA chains).
// Fallback: exact R14 asm path if the builtin is unavailable.
// ============================================================================
struct __align__(16) GSmem {
    ushort_t As[2][BT * BK];   // 32KB each: As[0]@0, As[1]@32768
    ushort_t Bs[2][BT * BK];   // Bs[0]@65536, Bs[1]@98304
    float red[8];
};

#if __has_builtin(__builtin_amdgcn_ds_read_tr16_b64)
#define HAVE_TR_BUILTIN 1
typedef __attribute__((address_space(3))) s16x4 lds_s16x4;
__device__ __forceinline__ s16x4 tr_read(unsigned byte_addr) {
    return __builtin_amdgcn_ds_read_tr16_b64((lds_s16x4*)(unsigned long)byte_addr);
}
#else
#define HAVE_TR_BUILTIN 0
#endif

__device__ __forceinline__ void load_tile(const float* __restrict__ p, int k0,
                                          int krb, int gr, float4* fl) {
    #pragma unroll
    for (int it = 0; it < 4; ++it) {
        const float* q = p + (size_t)(k0 + krb + it) * N_ + gr * 8;
        fl[2 * it]     = *reinterpret_cast<const float4*>(q);
        fl[2 * it + 1] = *reinterpret_cast<const float4*>(q + 4);
    }
}

__device__ __forceinline__ void flush_tile(char* lds, int krb, int gr, const float4* fl) {
    #pragma unroll
    for (int it = 0; it < 4; ++it) {
        const int k = krb + it;
        const float4& f0 = fl[2 * it];
        const float4& f1 = fl[2 * it + 1];
        __hip_bfloat162 h0 = __float22bfloat162_rn(make_float2(f0.x, f0.y));
        __hip_bfloat162 h1 = __float22bfloat162_rn(make_float2(f0.z, f0.w));
        __hip_bfloat162 h2 = __float22bfloat162_rn(make_float2(f1.x, f1.y));
        __hip_bfloat162 h3 = __float22bfloat162_rn(make_float2(f1.z, f1.w));
        i32x4 v = { *reinterpret_cast<const int*>(&h0), *reinterpret_cast<const int*>(&h1),
                    *reinterpret_cast<const int*>(&h2), *reinterpret_cast<const int*>(&h3) };
        *reinterpret_cast<i32x4*>(lds + k * 512 + 16 * (gr ^ (2 * (k & 3)))) = v;
    }
}

__global__ __launch_bounds__(512, 2)
void fused_gemm_max_kernel(const float* __restrict__ e1, const float* __restrict__ e2,
                           float* __restrict__ out) {
    __shared__ GSmem sm;
    const int wg  = blockIdx.x;
    const int swz = (wg & 7) * 64 + (wg >> 3);   // XCD swizzle (512 % 8 == 0)
    const int b    = swz >> 4;
    const int tile = swz & 15;
    const int tn = (tile >> 2) * BT;
    const int tc = (tile & 3) * BT;

    const int t    = threadIdx.x;
    const int lane = t & 63;
    const int wave = t >> 6;
    const int wrow = (wave >> 2) * 128;
    const int wcol = (wave & 3) * 64;

    const int krb = (t >> 5) * 4;
    const int gr  = t & 31;

    // tr_read per-lane geometry (R5-verified pattern, stride scaled to 512B)
    const int c = lane & 15, g = lane >> 4;
    const int r = c >> 2, d = (c >> 1) & 1, h = c & 1;

    unsigned tbA[8], tbB[4];
    #pragma unroll
    for (int m = 0; m < 8; ++m)
        tbA[m] = (unsigned)((8 * g + r) * 512
               + 16 * ((((wrow >> 3) + 2 * m + d) ^ (2 * r))) + 8 * h);
    #pragma unroll
    for (int n = 0; n < 4; ++n)
        tbB[n] = (unsigned)(65536 + (8 * g + r) * 512
               + 16 * ((((wcol >> 3) + 2 * n + d) ^ (2 * r))) + 8 * h);
    const unsigned ldsbase = (unsigned)(uintptr_t)&sm.As[0][0];

    const float* Ap = e1 + (size_t)b * D_ * N_ + tn;
    const float* Bp = e2 + (size_t)b * D_ * M_ + tc;

    f32x4 acc[8][4] = {};
    float4 fl[8];

    // Prologue: A0 -> LDS0, B0 -> LDS0, issue A1 loads into fl.
    load_tile(Ap, 0, krb, gr, fl);
    flush_tile((char*)sm.As[0], krb, gr, fl);
    load_tile(Bp, 0, krb, gr, fl);
    flush_tile((char*)sm.Bs[0], krb, gr, fl);
    load_tile(Ap, BK, krb, gr, fl);
    __syncthreads();

    int cur = 0;
    #pragma unroll 1
    for (int ks = 0; ks < NSTEP; ++ks) {
        const unsigned off = ldsbase + (unsigned)cur * 32768u;
        const bool has_next = (ks < NSTEP - 1);

        #pragma unroll
        for (int kk = 0; kk < 2; ++kk) {
#if HAVE_TR_BUILTIN
            // Compiler-scheduled: builtin reads, dataflow-ordered MFMAs.
            bf16x8 af[8], bf[4];
            #pragma unroll
            for (int m = 0; m < 8; ++m) {
                s16x4 lo = tr_read(tbA[m] + off + kk * 16384);
                s16x4 hi = tr_read(tbA[m] + off + kk * 16384 + 2048);
                af[m] = __builtin_shufflevector(lo, hi, 0, 1, 2, 3, 4, 5, 6, 7);
            }
            #pragma unroll
            for (int n = 0; n < 4; ++n) {
                s16x4 lo = tr_read(tbB[n] + off + kk * 16384);
                s16x4 hi = tr_read(tbB[n] + off + kk * 16384 + 2048);
                bf[n] = __builtin_shufflevector(lo, hi, 0, 1, 2, 3, 4, 5, 6, 7);
            }
            #pragma unroll
            for (int m = 0; m < 8; ++m)
                #pragma unroll
                for (int n = 0; n < 4; ++n)
                    acc[m][n] = __builtin_amdgcn_mfma_f32_16x16x32_bf16(
                        af[m], bf[n], acc[m][n], 0, 0, 0);
#else
            // R14 fallback: asm tr_reads + full drain before MFMA.
            s16x4 alo[8], ahi[8], blo[4], bhi[4];
            #pragma unroll
            for (int m = 0; m < 8; ++m) {
                asm volatile("ds_read_b64_tr_b16 %0, %1 offset:%2"
                             : "=v"(alo[m]) : "v"(tbA[m] + off), "n"(kk * 16384));
                asm volatile("ds_read_b64_tr_b16 %0, %1 offset:%2"
                             : "=v"(ahi[m]) : "v"(tbA[m] + off), "n"(kk * 16384 + 2048));
            }
            #pragma unroll
            for (int n = 0; n < 4; ++n) {
                asm volatile("ds_read_b64_tr_b16 %0, %1 offset:%2"
                             : "=v"(blo[n]) : "v"(tbB[n] + off), "n"(kk * 16384));
                asm volatile("ds_read_b64_tr_b16 %0, %1 offset:%2"
                             : "=v"(bhi[n]) : "v"(tbB[n] + off), "n"(kk * 16384 + 2048));
            }
            asm volatile("s_waitcnt lgkmcnt(0)" ::: "memory");
            __builtin_amdgcn_sched_barrier(0);
            bf16x8 af[8], bf[4];
            #pragma unroll
            for (int m = 0; m < 8; ++m)
                af[m] = __builtin_shufflevector(alo[m], ahi[m], 0, 1, 2, 3, 4, 5, 6, 7);
            #pragma unroll
            for (int n = 0; n < 4; ++n)
                bf[n] = __builtin_shufflevector(blo[n], bhi[n], 0, 1, 2, 3, 4, 5, 6, 7);
            __builtin_amdgcn_s_setprio(1);
            #pragma unroll
            for (int m = 0; m < 8; ++m)
                #pragma unroll
                for (int n = 0; n < 4; ++n)
                    acc[m][n] = __builtin_amdgcn_mfma_f32_16x16x32_bf16(
                        af[m], bf[n], acc[m][n], 0, 0, 0);
            __builtin_amdgcn_s_setprio(0);
#endif
            // Time-shared staging between the two MFMA clusters:
            if (kk == 0 && has_next) {
                flush_tile((char*)sm.As[cur ^ 1], krb, gr, fl);  // A(ks+1) -> LDS
                load_tile(Bp, (ks + 1) * BK, krb, gr, fl);       // issue B(ks+1) loads
            }
        }
        if (has_next) {
            flush_tile((char*)sm.Bs[cur ^ 1], krb, gr, fl);      // B(ks+1) -> LDS
            if (ks < NSTEP - 2)
                load_tile(Ap, (ks + 2) * BK, krb, gr, fl);       // issue A(ks+2) loads
        }
        __syncthreads();   // drains ds_writes (lgkmcnt 0) + barrier
        cur ^= 1;
    }

    // Max over this thread's 128 accumulator values.
    float tmax = acc[0][0][0];
    #pragma unroll
    for (int m = 0; m < 8; ++m)
        #pragma unroll
        for (int n = 0; n < 4; ++n)
            #pragma unroll
            for (int i = 0; i < 4; ++i)
                tmax = fmaxf(tmax, acc[m][n][i]);
    #pragma unroll
    for (int off2 = 32; off2; off2 >>= 1)
        tmax = fmaxf(tmax, __shfl_xor(tmax, off2));
    if (lane == 0) sm.red[wave] = tmax;
    __syncthreads();
    if (t == 0) {
        float m8 = sm.red[0];
        #pragma unroll
        for (int w = 1; w < 8; ++w) m8 = fmaxf(m8, sm.red[w]);
        atomicMax(reinterpret_cast<unsigned*>(out) + b, map_f(m8));
    }
}

__global__ void finalize_kernel(float* out) {
    const int i = threadIdx.x;
    unsigned u = reinterpret_cast<unsigned*>(out)[i];
    out[i] = __uint_as_float((u & 0x80000000u) ? (u ^ 0x80000000u) : ~u);
}

extern "C" void kernel_launch(void* const* d_in, const int* in_sizes, int n_in,
                              void* d_out, int out_size, void* d_ws, size_t ws_size,
                              hipStream_t stream) {
    const float* e1 = (const float*)d_in[0];
    const float* e2 = (const float*)d_in[1];
    float* out = (float*)d_out;

    (void)hipMemsetAsync(d_out, 0, B_ * sizeof(float), stream);  // 0 == -inf under map_f

    fused_gemm_max_kernel<<<dim3(512), 512, 0, stream>>>(e1, e2, out);
    finalize_kernel<<<1, B_, 0, stream>>>(out);
}

// Round 19
// 51.128 us; speedup vs baseline: 1.0890x; 1.0298x over previous
//
#include <hip/hip_runtime.h>
#include <hip/hip_bf16.h>

#define B_ 32
#define D_ 512
#define N_ 1024
#define M_ 1024
#define BT 256
#define BK 64
#define NIT 16            // 2 tiles x 8 K-steps, continuous

typedef __attribute__((ext_vector_type(8))) short bf16x8;
typedef __attribute__((ext_vector_type(4))) short s16x4;
typedef __attribute__((ext_vector_type(4))) float f32x4;
typedef __attribute__((ext_vector_type(4))) int   i32x4;
typedef unsigned short ushort_t;

__device__ __forceinline__ unsigned map_f(float f) {
    unsigned b = __float_as_uint(f);
    return (b & 0x80000000u) ? ~b : (b | 0x80000000u);
}

// ============================================================================
// Fused fp32->bf16 GEMM-max: PERSISTENT 2-tile blocks.
// Grid 256 = 1 block/CU; each block computes two 256x256 tiles sharing the
// same A panel (tn, tc0) and (tn, tc0+256) as ONE continuous 16-iter K-loop:
// one prologue, no inter-block gap, dbuf pipeline rolls across the boundary
// (only the B global pointer switches at iter 8; acc folds into tmax there).
// Everything else is R14 verbatim (verified 52.7us): [k=64][j=256] bf16 LDS
// tile, granule swizzle k*512 + 16*(gr^(2*(k&3))), b128 writes, asm
// ds_read_b64_tr_b16 fragment reads, one fl staging buffer time-shared.
// ============================================================================
struct __align__(16) GSmem {
    ushort_t As[2][BT * BK];   // 32KB each: As[0]@0, As[1]@32768
    ushort_t Bs[2][BT * BK];   // Bs[0]@65536, Bs[1]@98304
    float red[8];
};

__device__ __forceinline__ void load_tile(const float* __restrict__ p, int k0,
                                          int krb, int gr, float4* fl) {
    #pragma unroll
    for (int it = 0; it < 4; ++it) {
        const float* q = p + (size_t)(k0 + krb + it) * N_ + gr * 8;
        fl[2 * it]     = *reinterpret_cast<const float4*>(q);
        fl[2 * it + 1] = *reinterpret_cast<const float4*>(q + 4);
    }
}

__device__ __forceinline__ void flush_tile(char* lds, int krb, int gr, const float4* fl) {
    #pragma unroll
    for (int it = 0; it < 4; ++it) {
        const int k = krb + it;
        const float4& f0 = fl[2 * it];
        const float4& f1 = fl[2 * it + 1];
        __hip_bfloat162 h0 = __float22bfloat162_rn(make_float2(f0.x, f0.y));
        __hip_bfloat162 h1 = __float22bfloat162_rn(make_float2(f0.z, f0.w));
        __hip_bfloat162 h2 = __float22bfloat162_rn(make_float2(f1.x, f1.y));
        __hip_bfloat162 h3 = __float22bfloat162_rn(make_float2(f1.z, f1.w));
        i32x4 v = { *reinterpret_cast<const int*>(&h0), *reinterpret_cast<const int*>(&h1),
                    *reinterpret_cast<const int*>(&h2), *reinterpret_cast<const int*>(&h3) };
        *reinterpret_cast<i32x4*>(lds + k * 512 + 16 * (gr ^ (2 * (k & 3)))) = v;
    }
}

__global__ __launch_bounds__(512, 2)
void fused_gemm_max_kernel(const float* __restrict__ e1, const float* __restrict__ e2,
                           float* __restrict__ out) {
    __shared__ GSmem sm;
    const int wg  = blockIdx.x;
    const int swz = (wg & 7) * 32 + (wg >> 3);   // XCD swizzle (256 % 8 == 0)
    const int b    = swz >> 3;                   // 8 tile-pairs per batch
    const int pair = swz & 7;
    const int tn  = (pair >> 1) * BT;            // shared A panel
    const int tc0 = (pair & 1) * 512;            // B panels: tc0, tc0+256

    const int t    = threadIdx.x;
    const int lane = t & 63;
    const int wave = t >> 6;
    const int wrow = (wave >> 2) * 128;
    const int wcol = (wave & 3) * 64;

    const int krb = (t >> 5) * 4;
    const int gr  = t & 31;

    // tr_read per-lane geometry (R5-verified pattern, stride scaled to 512B)
    const int c = lane & 15, g = lane >> 4;
    const int r = c >> 2, d = (c >> 1) & 1, h = c & 1;

    unsigned tbA[8], tbB[4];
    #pragma unroll
    for (int m = 0; m < 8; ++m)
        tbA[m] = (unsigned)((8 * g + r) * 512
               + 16 * ((((wrow >> 3) + 2 * m + d) ^ (2 * r))) + 8 * h);
    #pragma unroll
    for (int n = 0; n < 4; ++n)
        tbB[n] = (unsigned)(65536 + (8 * g + r) * 512
               + 16 * ((((wcol >> 3) + 2 * n + d) ^ (2 * r))) + 8 * h);
    const unsigned ldsbase = (unsigned)(uintptr_t)&sm.As[0][0];

    const float* Ap  = e1 + (size_t)b * D_ * N_ + tn;
    const float* Bp0 = e2 + (size_t)b * D_ * M_ + tc0;
    const float* Bp1 = Bp0 + BT;

    f32x4 acc[8][4] = {};
    float4 fl[8];
    float tmax = -3.4e38f;

    // Prologue (once for both tiles): A0 -> LDS0, B0 -> LDS0, issue A(1) loads.
    load_tile(Ap, 0, krb, gr, fl);
    flush_tile((char*)sm.As[0], krb, gr, fl);
    load_tile(Bp0, 0, krb, gr, fl);
    flush_tile((char*)sm.Bs[0], krb, gr, fl);
    load_tile(Ap, BK, krb, gr, fl);
    asm volatile("s_waitcnt lgkmcnt(0)" ::: "memory");
    __builtin_amdgcn_s_barrier();

    int cur = 0;
    #pragma unroll 1
    for (int it = 0; it < NIT; ++it) {
        const unsigned off = ldsbase + (unsigned)cur * 32768u;
        const bool has_next = (it < NIT - 1);

        #pragma unroll
        for (int kk = 0; kk < 2; ++kk) {
            s16x4 alo[8], ahi[8], blo[4], bhi[4];
            #pragma unroll
            for (int m = 0; m < 8; ++m) {
                asm volatile("ds_read_b64_tr_b16 %0, %1 offset:%2"
                             : "=v"(alo[m]) : "v"(tbA[m] + off), "n"(kk * 16384));
                asm volatile("ds_read_b64_tr_b16 %0, %1 offset:%2"
                             : "=v"(ahi[m]) : "v"(tbA[m] + off), "n"(kk * 16384 + 2048));
            }
            #pragma unroll
            for (int n = 0; n < 4; ++n) {
                asm volatile("ds_read_b64_tr_b16 %0, %1 offset:%2"
                             : "=v"(blo[n]) : "v"(tbB[n] + off), "n"(kk * 16384));
                asm volatile("ds_read_b64_tr_b16 %0, %1 offset:%2"
                             : "=v"(bhi[n]) : "v"(tbB[n] + off), "n"(kk * 16384 + 2048));
            }
            asm volatile("s_waitcnt lgkmcnt(0)" ::: "memory");
            __builtin_amdgcn_sched_barrier(0);
            bf16x8 af[8], bf[4];
            #pragma unroll
            for (int m = 0; m < 8; ++m)
                af[m] = __builtin_shufflevector(alo[m], ahi[m], 0, 1, 2, 3, 4, 5, 6, 7);
            #pragma unroll
            for (int n = 0; n < 4; ++n)
                bf[n] = __builtin_shufflevector(blo[n], bhi[n], 0, 1, 2, 3, 4, 5, 6, 7);
            __builtin_amdgcn_s_setprio(1);
            #pragma unroll
            for (int m = 0; m < 8; ++m)
                #pragma unroll
                for (int n = 0; n < 4; ++n)
                    acc[m][n] = __builtin_amdgcn_mfma_f32_16x16x32_bf16(
                        af[m], bf[n], acc[m][n], 0, 0, 0);
            __builtin_amdgcn_s_setprio(0);

            // Time-shared staging between the two MFMA clusters:
            if (kk == 0 && has_next) {
                flush_tile((char*)sm.As[cur ^ 1], krb, gr, fl);   // A(it+1) -> LDS
                const float* bp = (it + 1 < 8) ? Bp0 : Bp1;
                load_tile(bp, ((it + 1) & 7) * BK, krb, gr, fl);  // issue B(it+1)
            }
        }

        // Tile boundary: fold tile 0 into tmax, reset accumulator.
        if (it == 7) {
            #pragma unroll
            for (int m = 0; m < 8; ++m)
                #pragma unroll
                for (int n = 0; n < 4; ++n) {
                    #pragma unroll
                    for (int i = 0; i < 4; ++i)
                        tmax = fmaxf(tmax, acc[m][n][i]);
                    acc[m][n] = f32x4{0.f, 0.f, 0.f, 0.f};
                }
        }

        if (has_next) {
            flush_tile((char*)sm.Bs[cur ^ 1], krb, gr, fl);       // B(it+1) -> LDS
            if (it < NIT - 2)
                load_tile(Ap, ((it + 2) & 7) * BK, krb, gr, fl);  // issue A(it+2)
        }
        asm volatile("s_waitcnt lgkmcnt(0)" ::: "memory");        // ds_writes drained
        __builtin_amdgcn_s_barrier();
        cur ^= 1;
    }

    // Fold tile 1; wave + block reduce; one atomic per block (both tiles same b).
    #pragma unroll
    for (int m = 0; m < 8; ++m)
        #pragma unroll
        for (int n = 0; n < 4; ++n)
            #pragma unroll
            for (int i = 0; i < 4; ++i)
                tmax = fmaxf(tmax, acc[m][n][i]);
    #pragma unroll
    for (int off2 = 32; off2; off2 >>= 1)
        tmax = fmaxf(tmax, __shfl_xor(tmax, off2));
    if (lane == 0) sm.red[wave] = tmax;
    __syncthreads();
    if (t == 0) {
        float m8 = sm.red[0];
        #pragma unroll
        for (int w = 1; w < 8; ++w) m8 = fmaxf(m8, sm.red[w]);
        atomicMax(reinterpret_cast<unsigned*>(out) + b, map_f(m8));
    }
}

__global__ void finalize_kernel(float* out) {
    const int i = threadIdx.x;
    unsigned u = reinterpret_cast<unsigned*>(out)[i];
    out[i] = __uint_as_float((u & 0x80000000u) ? (u ^ 0x80000000u) : ~u);
}

extern "C" void kernel_launch(void* const* d_in, const int* in_sizes, int n_in,
                              void* d_out, int out_size, void* d_ws, size_t ws_size,
                              hipStream_t stream) {
    const float* e1 = (const float*)d_in[0];
    const float* e2 = (const float*)d_in[1];
    float* out = (float*)d_out;

    (void)hipMemsetAsync(d_out, 0, B_ * sizeof(float), stream);  // 0 == -inf under map_f

    fused_gemm_max_kernel<<<dim3(256), 512, 0, stream>>>(e1, e2, out);
    finalize_kernel<<<1, B_, 0, stream>>>(out);
}